// Round 9
// baseline (1043.390 us; speedup 1.0000x reference)
//
#include <hip/hip_runtime.h>
#include <hip/hip_bf16.h>

// Problem constants (match reference)
#define E_LINKS 131072
#define M_PAIRS 1048576
#define DDIM    64
#define GG      1024
#define RUNITS  256
#define TITER   8

typedef __attribute__((ext_vector_type(8))) short bf16x8;
typedef __attribute__((ext_vector_type(4))) float f32x4;
typedef __attribute__((ext_vector_type(16))) float f32x16;

__device__ inline unsigned short f2bf(float f){
  union { float f; unsigned int u; } v; v.f = f;
  unsigned int u = v.u;
  unsigned int r = (u + 0x7FFFu + ((u >> 16) & 1u)) >> 16;
  return (unsigned short)r;
}
__device__ inline float bf2f(unsigned short u){
  union { unsigned int u; float f; } v; v.u = ((unsigned int)u) << 16; return v.f;
}
__device__ inline float selu_f(float x){
  return x > 0.f ? 1.0507009873554805f * x
                 : 1.7580993408473766f * (__expf(x) - 1.f);
}
__device__ inline float sigmoid_f(float x){ return 1.f / (1.f + __expf(-x)); }
__device__ inline float tanh_f(float x){
  float xc = fminf(fmaxf(x, -15.f), 15.f);
  float e2 = __expf(2.f * xc);
  return (e2 - 1.f) / (e2 + 1.f);
}

__device__ inline bf16x8 packbf8f(float4 u0, float4 u1){
  bf16x8 r;
  r[0] = (short)f2bf(u0.x); r[1] = (short)f2bf(u0.y);
  r[2] = (short)f2bf(u0.z); r[3] = (short)f2bf(u0.w);
  r[4] = (short)f2bf(u1.x); r[5] = (short)f2bf(u1.y);
  r[6] = (short)f2bf(u1.z); r[7] = (short)f2bf(u1.w);
  return r;
}

__device__ inline f32x16 zero16(){
  f32x16 v;
  #pragma unroll
  for (int i = 0; i < 16; i++) v[i] = 0.f;
  return v;
}

// ---------------- preprocessing ----------------

__global__ void k_zero(int* __restrict__ counts){
  int i = blockIdx.x * blockDim.x + threadIdx.x;
  if (i < E_LINKS) counts[i] = 0;
}

__global__ void k_hist(const int* __restrict__ second, int* __restrict__ counts){
  int i = blockIdx.x * blockDim.x + threadIdx.x;
  if (i < M_PAIRS) atomicAdd(&counts[second[i]], 1);
}

__global__ __launch_bounds__(256) void k_scan_reduce(const int* __restrict__ counts,
    int* __restrict__ partials){
  __shared__ int s[256];
  int t = threadIdx.x;
  int i = blockIdx.x * 256 + t;
  s[t] = counts[i];
  __syncthreads();
  #pragma unroll
  for (int off = 128; off > 0; off >>= 1){
    if (t < off) s[t] += s[t + off];
    __syncthreads();
  }
  if (t == 0) partials[blockIdx.x] = s[0];
}

__global__ __launch_bounds__(512) void k_scan_part(int* __restrict__ partials){
  __shared__ int s[512];
  int t = threadIdx.x;
  int v = partials[t];
  s[t] = v;
  __syncthreads();
  for (int off = 1; off < 512; off <<= 1){
    int u = (t >= off) ? s[t - off] : 0;
    __syncthreads();
    s[t] += u;
    __syncthreads();
  }
  partials[t] = s[t] - v;
}

__global__ __launch_bounds__(256) void k_scan_apply(const int* __restrict__ counts,
    const int* __restrict__ partials, int* __restrict__ offsets,
    int* __restrict__ cursor){
  __shared__ int s[256];
  int t = threadIdx.x;
  int i = blockIdx.x * 256 + t;
  int c = counts[i];
  s[t] = c;
  __syncthreads();
  for (int off = 1; off < 256; off <<= 1){
    int u = (t >= off) ? s[t - off] : 0;
    __syncthreads();
    s[t] += u;
    __syncthreads();
  }
  int run = partials[blockIdx.x] + s[t] - c;
  offsets[i] = run;
  cursor[i] = run;
  if (i == E_LINKS - 1) offsets[E_LINKS] = run + c;
}

__global__ void k_goffs(const int* __restrict__ gid, int* __restrict__ goffs){
  int i = blockIdx.x * blockDim.x + threadIdx.x;
  if (i >= E_LINKS) return;
  int g = gid[i];
  int gp = (i == 0) ? -1 : gid[i - 1];
  for (int x = gp + 1; x <= g; x++) goffs[x] = i;
  if (i == E_LINKS - 1){
    for (int x = g + 1; x <= GG; x++) goffs[x] = E_LINKS;
  }
}

__global__ void k_scatter(const int* __restrict__ first, const int* __restrict__ second,
    int* __restrict__ cursor, int* __restrict__ srcs){
  int i = blockIdx.x * blockDim.x + threadIdx.x;
  if (i < M_PAIRS){
    int e = second[i];
    int slot = atomicAdd(&cursor[e], 1);
    srcs[slot] = first[i];
  }
}

// Build transposed bf16 weights + combined biases.
__global__ void k_prepw(const float* __restrict__ W_msg,
    const float* __restrict__ gk, const float* __restrict__ grk,
    const float* __restrict__ bi, const float* __restrict__ br,
    unsigned short* __restrict__ WzrT, unsigned short* __restrict__ WxhT,
    unsigned short* __restrict__ WhhT, unsigned short* __restrict__ WcT,
    float* __restrict__ bzr, float* __restrict__ bxh, float* __restrict__ bhh){
  int i = blockIdx.x * blockDim.x + threadIdx.x;
  if (i < 16384){
    int c = i >> 7, k = i & 127;
    float v = (k < 64) ? gk[k * 192 + c] : grk[(k - 64) * 192 + c];
    WzrT[i] = f2bf(v);
  } else if (i < 20480){
    int j = i - 16384; int c = j >> 6, k = j & 63;
    WxhT[j] = f2bf(gk[k * 192 + 128 + c]);
  } else if (i < 24576){
    int j = i - 20480; int c = j >> 6, k = j & 63;
    WhhT[j] = f2bf(grk[k * 192 + 128 + c]);
  } else if (i < 32768){
    int j = i - 24576; int c = j >> 6, k = j & 63;
    float v = (c < 64) ? W_msg[k * 64 + c] : W_msg[(64 + k) * 64 + (c - 64)];
    WcT[j] = f2bf(v);
  } else if (i < 33024){
    int j = i - 32768;
    if (j < 128) bzr[j] = bi[j] + br[j];
    else if (j < 192) bxh[j - 128] = bi[j];
    else bhh[j - 192] = br[j - 64];
  }
}

// ---------------- main loop kernels ----------------

// AB[E,128] = h[E,64] @ Wc[64,128] (+ b_msg on cols>=64); h read as f32.
__global__ __launch_bounds__(256) void k_ab0(const float* __restrict__ hf,
    const unsigned short* __restrict__ WcT, const float* __restrict__ b_msg,
    unsigned short* __restrict__ AB){
  int wave = threadIdx.x >> 6, lane = threadIdx.x & 63;
  int row0 = (blockIdx.x * 4 + wave) * 16;
  int lr = lane & 15, lg = lane >> 4;
  f32x4 acc[8];
  #pragma unroll
  for (int i = 0; i < 8; i++) acc[i] = (f32x4){0.f, 0.f, 0.f, 0.f};
  #pragma unroll
  for (int s = 0; s < 2; s++){
    int kb = s * 32 + lg * 8;
    const float* p = hf + (size_t)(row0 + lr) * 64 + kb;
    bf16x8 a = packbf8f(*(const float4*)p, *(const float4*)(p + 4));
    #pragma unroll
    for (int ct = 0; ct < 8; ct++){
      bf16x8 b = *(const bf16x8*)(WcT + (ct * 16 + lr) * 64 + kb);
      acc[ct] = __builtin_amdgcn_mfma_f32_16x16x32_bf16(a, b, acc[ct], 0, 0, 0);
    }
  }
  #pragma unroll
  for (int ct = 0; ct < 8; ct++){
    int col = ct * 16 + lr;
    float bias = (col >= 64) ? b_msg[col - 64] : 0.f;
    #pragma unroll
    for (int q = 0; q < 4; q++){
      int row = row0 + lg * 4 + q;
      AB[(size_t)row * 128 + col] = f2bf(acc[ct][q] + bias);
    }
  }
}

// Fully fused iteration: gather+aggregate (from AB_in of the PREVIOUS launch),
// GRU via 32x32x16 MFMA, optional AB_out for the next iteration.
// 32 rows/wave. LDS per wave: one 8704B region, time-multiplexed:
//   [phase A] ash: bf16 [32][64] swizzled agg tile (gather result)
//   [phase B] hsh: f32 [32][68] hold tile (after az reads, barrier 1)
//   [phase C] tsh: bf16 [32][64] swizzled hn tile (after hold reads, barrier 2)
// AB double-buffered across launches: gather reads ABi while epilogue writes ABo.
// h updated in place (each block touches only its own rows).
template<bool WITH_AB>
__global__ __launch_bounds__(256, 4) void k_fused(
    const unsigned short* __restrict__ ABi,
    const int* __restrict__ offsets, const int* __restrict__ srcs,
    const float* h_in, float* h_out,
    const unsigned short* __restrict__ WzrT, const unsigned short* __restrict__ WxhT,
    const unsigned short* __restrict__ WhhT, const unsigned short* __restrict__ WcT,
    const float* __restrict__ bzr, const float* __restrict__ bxh,
    const float* __restrict__ bhh,
    const float* __restrict__ b_msg, unsigned short* __restrict__ ABo){
  __shared__ float hsh[4][32][68];   // 34816B/block; multiplexed per phase
  int wave = threadIdx.x >> 6, lane = threadIdx.x & 63;
  int row0 = (blockIdx.x * 4 + wave) * 32;
  int lc = lane & 31, lh = lane >> 5;
  unsigned short* ash = (unsigned short*)&hsh[wave][0][0]; // [32][64] bf16 swizzled

  // ---- issue h loads early (latency hidden under the gather) ----
  const float* hrow = h_in + (size_t)(row0 + lc) * 64 + lh * 8;
  float4 hu0[4], hu1[4];
  #pragma unroll
  for (int s = 0; s < 4; s++){
    hu0[s] = *(const float4*)(hrow + s * 16);
    hu1[s] = *(const float4*)(hrow + s * 16 + 4);
  }

  // ---- phase A: gather/aggregate this wave's 32 rows into ash ----
  {
    int g = lane >> 4, d = lane & 15;   // 4 groups x 16 lanes
    #pragma unroll 1
    for (int eo = 0; eo < 8; eo++){
      int r = g * 8 + eo;
      int e = row0 + r;
      ushort4 bq = *(const ushort4*)(ABi + (size_t)e * 128 + 64 + d * 4);
      float b0 = bf2f(bq.x), b1 = bf2f(bq.y), b2 = bf2f(bq.z), b3 = bf2f(bq.w);
      int beg = offsets[e], end = offsets[e + 1];
      float a0 = 0.f, a1 = 0.f, a2 = 0.f, a3 = 0.f;
      int i = beg;
      for (; i + 1 < end; i += 2){
        int s0 = srcs[i], s1 = srcs[i + 1];
        ushort4 q0 = *(const ushort4*)(ABi + (size_t)s0 * 128 + d * 4);
        ushort4 q1 = *(const ushort4*)(ABi + (size_t)s1 * 128 + d * 4);
        a0 += selu_f(bf2f(q0.x) + b0);
        a1 += selu_f(bf2f(q0.y) + b1);
        a2 += selu_f(bf2f(q0.z) + b2);
        a3 += selu_f(bf2f(q0.w) + b3);
        a0 += selu_f(bf2f(q1.x) + b0);
        a1 += selu_f(bf2f(q1.y) + b1);
        a2 += selu_f(bf2f(q1.z) + b2);
        a3 += selu_f(bf2f(q1.w) + b3);
      }
      if (i < end){
        int s0 = srcs[i];
        ushort4 q0 = *(const ushort4*)(ABi + (size_t)s0 * 128 + d * 4);
        a0 += selu_f(bf2f(q0.x) + b0);
        a1 += selu_f(bf2f(q0.y) + b1);
        a2 += selu_f(bf2f(q0.z) + b2);
        a3 += selu_f(bf2f(q0.w) + b3);
      }
      // swizzled store: col = d*4 -> block d>>1, offset (d&1)*4
      ushort4 o;
      o.x = f2bf(a0); o.y = f2bf(a1); o.z = f2bf(a2); o.w = f2bf(a3);
      *(ushort4*)(ash + r * 64 + (((d >> 1) ^ (r & 7)) << 3) + (d & 1) * 4) = o;
    }
  }

  // ---- read agg A-fragments from ash (before hsh overwrites it) ----
  bf16x8 az[8];
  #pragma unroll
  for (int s = 0; s < 4; s++)
    az[s] = *(const bf16x8*)(ash + lc * 64 + (((s * 2 + lh) ^ (lc & 7)) << 3));

  __syncthreads();   // barrier 1: ash reads complete before hold tile writes

  // ---- phase B: stash fp32 holds + pack h A-fragments ----
  #pragma unroll
  for (int s = 0; s < 4; s++){
    az[4 + s] = packbf8f(hu0[s], hu1[s]);
    *(float4*)(&hsh[wave][lc][s * 16 + lh * 8]) = hu0[s];
    *(float4*)(&hsh[wave][lc][s * 16 + lh * 8 + 4]) = hu1[s];
  }

  // ---- r-gate GEMM (zr tiles 2,3 -> cols 64..127) ----
  f32x16 ar0 = zero16(), ar1 = zero16();
  #pragma unroll
  for (int s = 0; s < 8; s++){
    const unsigned short* wk = WzrT + lh * 8 + s * 16;
    bf16x8 b2 = *(const bf16x8*)(wk + (size_t)(64 + lc) * 128);
    bf16x8 b3 = *(const bf16x8*)(wk + (size_t)(96 + lc) * 128);
    ar0 = __builtin_amdgcn_mfma_f32_32x32x16_bf16(az[s], b2, ar0, 0, 0, 0);
    ar1 = __builtin_amdgcn_mfma_f32_32x32x16_bf16(az[s], b3, ar1, 0, 0, 0);
  }

  float cv[2][16];

  // ---- cols 0..31: xh0 (A=agg), hh0 (A=h) -> cv[0] ----
  {
    f32x16 axh = zero16(), ahh = zero16();
    #pragma unroll
    for (int s = 0; s < 4; s++){
      const unsigned short* wx = WxhT + lh * 8 + s * 16;
      axh = __builtin_amdgcn_mfma_f32_32x32x16_bf16(az[s],
          *(const bf16x8*)(wx + (size_t)lc * 64), axh, 0, 0, 0);
      const unsigned short* wh = WhhT + lh * 8 + s * 16;
      ahh = __builtin_amdgcn_mfma_f32_32x32x16_bf16(az[4 + s],
          *(const bf16x8*)(wh + (size_t)lc * 64), ahh, 0, 0, 0);
    }
    float brv = bzr[64 + lc], bx = bxh[lc], bh = bhh[lc];
    #pragma unroll
    for (int r = 0; r < 16; r++){
      float rr = sigmoid_f(ar0[r] + brv);
      cv[0][r] = tanh_f(axh[r] + bx + rr * (ahh[r] + bh));
    }
  }

  // ---- cols 32..63: xh1, hh1 -> cv[1] ----
  {
    f32x16 axh = zero16(), ahh = zero16();
    #pragma unroll
    for (int s = 0; s < 4; s++){
      const unsigned short* wx = WxhT + lh * 8 + s * 16;
      axh = __builtin_amdgcn_mfma_f32_32x32x16_bf16(az[s],
          *(const bf16x8*)(wx + (size_t)(32 + lc) * 64), axh, 0, 0, 0);
      const unsigned short* wh = WhhT + lh * 8 + s * 16;
      ahh = __builtin_amdgcn_mfma_f32_32x32x16_bf16(az[4 + s],
          *(const bf16x8*)(wh + (size_t)(32 + lc) * 64), ahh, 0, 0, 0);
    }
    float brv = bzr[64 + 32 + lc], bx = bxh[32 + lc], bh = bhh[32 + lc];
    #pragma unroll
    for (int r = 0; r < 16; r++){
      float rr = sigmoid_f(ar1[r] + brv);
      cv[1][r] = tanh_f(axh[r] + bx + rr * (ahh[r] + bh));
    }
  }

  // ---- z-gate GEMM (zr tiles 0,1 -> cols 0..63) ----
  f32x16 azt0 = zero16(), azt1 = zero16();
  #pragma unroll
  for (int s = 0; s < 8; s++){
    const unsigned short* wk = WzrT + lh * 8 + s * 16;
    bf16x8 b0 = *(const bf16x8*)(wk + (size_t)lc * 128);
    bf16x8 b1 = *(const bf16x8*)(wk + (size_t)(32 + lc) * 128);
    azt0 = __builtin_amdgcn_mfma_f32_32x32x16_bf16(az[s], b0, azt0, 0, 0, 0);
    azt1 = __builtin_amdgcn_mfma_f32_32x32x16_bf16(az[s], b1, azt1, 0, 0, 0);
  }

  // ---- fold z + holds -> final v ----
  {
    float bz0 = bzr[lc], bz1 = bzr[32 + lc];
    #pragma unroll
    for (int r = 0; r < 16; r++){
      int rl = (r & 3) + 8 * (r >> 2) + 4 * lh;
      float h0 = hsh[wave][rl][lc];
      float h1 = hsh[wave][rl][32 + lc];
      float z0 = sigmoid_f(azt0[r] + bz0);
      float z1 = sigmoid_f(azt1[r] + bz1);
      cv[0][r] = z0 * h0 + (1.f - z0) * cv[0][r];
      cv[1][r] = z1 * h1 + (1.f - z1) * cv[1][r];
    }
  }

  __syncthreads();   // barrier 2: hold reads complete before tsh overwrites

  // ---- write h_out + stash hn (swizzled) ----
  unsigned short* tsh = ash;
  {
    int j0 = lc, j1 = 32 + lc;
    #pragma unroll
    for (int r = 0; r < 16; r++){
      int rl = (r & 3) + 8 * (r >> 2) + 4 * lh;
      size_t base = (size_t)(row0 + rl) * 64;
      h_out[base + j0] = cv[0][r];
      h_out[base + j1] = cv[1][r];
      if (WITH_AB){
        tsh[rl * 64 + (((j0 >> 3) ^ (rl & 7)) << 3) + (j0 & 7)] = f2bf(cv[0][r]);
        tsh[rl * 64 + (((j1 >> 3) ^ (rl & 7)) << 3) + (j1 & 7)] = f2bf(cv[1][r]);
      }
    }
  }

  if (WITH_AB){
    // AB GEMM: M=32, N=128, K=64; A = hn from swizzled tsh
    f32x16 acc[4];
    #pragma unroll
    for (int i = 0; i < 4; i++) acc[i] = zero16();
    #pragma unroll
    for (int s = 0; s < 4; s++){
      int blk = ((s * 2 + lh) ^ (lc & 7)) << 3;
      bf16x8 a = *(const bf16x8*)(&tsh[lc * 64 + blk]);
      const unsigned short* wc = WcT + lh * 8 + s * 16;
      #pragma unroll
      for (int ct = 0; ct < 4; ct++){
        bf16x8 b = *(const bf16x8*)(wc + (size_t)(ct * 32 + lc) * 64);
        acc[ct] = __builtin_amdgcn_mfma_f32_32x32x16_bf16(a, b, acc[ct], 0, 0, 0);
      }
    }
    #pragma unroll
    for (int ct = 0; ct < 4; ct++){
      int col = ct * 32 + lc;
      float bias = (col >= 64) ? b_msg[col - 64] : 0.f;
      #pragma unroll
      for (int r = 0; r < 16; r++){
        int rl = (r & 3) + 8 * (r >> 2) + 4 * lh;
        ABo[(size_t)(row0 + rl) * 128 + col] = f2bf(acc[ct][r] + bias);
      }
    }
  }
}

// ---------------- readout ----------------

__global__ __launch_bounds__(256) void k_seg(const float* __restrict__ hf,
    const int* __restrict__ goff, float* __restrict__ gsum){
  int wave = threadIdx.x >> 6, lane = threadIdx.x & 63;
  int g = blockIdx.x * 4 + wave;
  int beg = goff[g], end = goff[g + 1];
  float acc = 0.f;
  for (int e = beg; e < end; e++) acc += hf[(size_t)e * 64 + lane];
  gsum[(size_t)g * 64 + lane] = acc;
}

__global__ __launch_bounds__(256) void k_mlp(const float* __restrict__ gsum,
    const float* __restrict__ W1, const float* __restrict__ b1,
    const float* __restrict__ W2, const float* __restrict__ b2,
    const float* __restrict__ W3, const float* __restrict__ b3,
    float* __restrict__ out){
  __shared__ float sg[64];
  __shared__ float sr1[256];
  __shared__ float sr2[256];
  __shared__ float wsum[4];
  int g = blockIdx.x, t = threadIdx.x;
  if (t < 64) sg[t] = gsum[(size_t)g * 64 + t];
  __syncthreads();
  float a = b1[t];
  #pragma unroll
  for (int k = 0; k < 64; k++) a += sg[k] * W1[k * 256 + t];
  sr1[t] = selu_f(a);
  __syncthreads();
  float b = b2[t];
  for (int k = 0; k < 256; k++) b += sr1[k] * W2[k * 256 + t];
  sr2[t] = selu_f(b);
  __syncthreads();
  float v = sr2[t] * W3[t];
  for (int off = 32; off > 0; off >>= 1) v += __shfl_down(v, off, 64);
  if ((t & 63) == 0) wsum[t >> 6] = v;
  __syncthreads();
  if (t == 0) out[g] = wsum[0] + wsum[1] + wsum[2] + wsum[3] + b3[0];
}

// ---------------- host ----------------

static inline size_t alignup(size_t x){ return (x + 255) & ~(size_t)255; }

extern "C" void kernel_launch(void* const* d_in, const int* in_sizes, int n_in,
                              void* d_out, int out_size, void* d_ws, size_t ws_size,
                              hipStream_t stream) {
  const float* states_action = (const float*)d_in[0];
  const int*   graph_ids     = (const int*)d_in[1];
  const int*   first         = (const int*)d_in[2];
  const int*   second        = (const int*)d_in[3];
  const float* W_msg         = (const float*)d_in[5];
  const float* b_msg         = (const float*)d_in[6];
  const float* gk            = (const float*)d_in[7];
  const float* grk           = (const float*)d_in[8];
  const float* bi            = (const float*)d_in[9];
  const float* br            = (const float*)d_in[10];
  const float* W1            = (const float*)d_in[11];
  const float* b1            = (const float*)d_in[12];
  const float* W2            = (const float*)d_in[13];
  const float* b2            = (const float*)d_in[14];
  const float* W3            = (const float*)d_in[15];
  const float* b3            = (const float*)d_in[16];
  float* out = (float*)d_out;

  char* ws = (char*)d_ws;
  size_t off = 0;
  float*          h_f32  = (float*)(ws + off);          off += alignup((size_t)E_LINKS * 64 * 4);
  unsigned short* AB0    = (unsigned short*)(ws + off); off += alignup((size_t)E_LINKS * 128 * 2);
  unsigned short* AB1    = (unsigned short*)(ws + off); off += alignup((size_t)E_LINKS * 128 * 2);
  unsigned short* WzrT   = (unsigned short*)(ws + off); off += alignup(128 * 128 * 2);
  unsigned short* WxhT   = (unsigned short*)(ws + off); off += alignup(64 * 64 * 2);
  unsigned short* WhhT   = (unsigned short*)(ws + off); off += alignup(64 * 64 * 2);
  unsigned short* WcT    = (unsigned short*)(ws + off); off += alignup(128 * 64 * 2);
  float*          bzr    = (float*)(ws + off);          off += alignup(128 * 4);
  float*          bxhv   = (float*)(ws + off);          off += alignup(64 * 4);
  float*          bhhv   = (float*)(ws + off);          off += alignup(64 * 4);
  int*            counts = (int*)(ws + off);            off += alignup((size_t)E_LINKS * 4);
  int*            offs   = (int*)(ws + off);            off += alignup(((size_t)E_LINKS + 1) * 4);
  int*            cursor = (int*)(ws + off);            off += alignup((size_t)E_LINKS * 4);
  int*            srcs   = (int*)(ws + off);            off += alignup((size_t)M_PAIRS * 4);
  int*            parts  = (int*)(ws + off);            off += alignup(512 * 4);
  int*            goffs  = (int*)(ws + off);            off += alignup(((size_t)GG + 1) * 4);
  float*          gsum   = (float*)(ws + off);          off += alignup((size_t)GG * 64 * 4);

  dim3 b256(256);

  // CSR preprocessing
  k_zero<<<dim3(E_LINKS / 256), b256, 0, stream>>>(counts);
  k_hist<<<dim3(M_PAIRS / 256), b256, 0, stream>>>(second, counts);
  k_scan_reduce<<<dim3(512), b256, 0, stream>>>(counts, parts);
  k_scan_part<<<dim3(1), dim3(512), 0, stream>>>(parts);
  k_scan_apply<<<dim3(512), b256, 0, stream>>>(counts, parts, offs, cursor);
  k_goffs<<<dim3(E_LINKS / 256), b256, 0, stream>>>(graph_ids, goffs);
  k_scatter<<<dim3(M_PAIRS / 256), b256, 0, stream>>>(first, second, cursor, srcs);

  // weights (33024 elements total -> 129 blocks)
  k_prepw<<<dim3(129), b256, 0, stream>>>(W_msg, gk, grk, bi, br,
      WzrT, WxhT, WhhT, WcT, bzr, bxhv, bhhv);

  // t=0 message precompute from initial h (= states_action)
  k_ab0<<<dim3(E_LINKS / 64), b256, 0, stream>>>(states_action, WcT, b_msg, AB0);

  // message passing: one fused kernel per iteration, AB double-buffered
  const unsigned short* abin = AB0;
  unsigned short* about = AB1;
  for (int t = 0; t < TITER; t++){
    const float* h_in = (t == 0) ? states_action : h_f32;
    if (t < TITER - 1){
      k_fused<true><<<dim3(E_LINKS / 128), b256, 0, stream>>>(abin, offs, srcs,
          h_in, h_f32, WzrT, WxhT, WhhT, WcT, bzr, bxhv, bhhv, b_msg, about);
      const unsigned short* tmp = abin;
      abin = about;
      about = (unsigned short*)tmp;
    } else {
      k_fused<false><<<dim3(E_LINKS / 128), b256, 0, stream>>>(abin, offs, srcs,
          h_in, h_f32, WzrT, WxhT, WhhT, WcT, bzr, bxhv, bhhv, b_msg, about);
    }
  }

  // readout
  k_seg<<<dim3(GG / 4), b256, 0, stream>>>(h_f32, goffs, gsum);
  k_mlp<<<dim3(GG), b256, 0, stream>>>(gsum, W1, b1, W2, b2, W3, b3, out);
}